// Round 1
// baseline (255.024 us; speedup 1.0000x reference)
//
#include <hip/hip_runtime.h>
#include <hip/hip_bf16.h>

#define EPS_BN 1e-5f
#define DW_THRESH 4.0f
#define PW_THRESH 0.001f

// Problem dims (fixed by the reference)
#define BATCH 32
#define CIN   256
#define COUT  512
#define HIN   56
#define WIN   56
#define HOUT  54
#define WOUT  54
#define NPIX  (HOUT*WOUT)     // 2916
#define XPIX  (HIN*WIN)       // 3136
#define PPT   12              // pixels per thread (12*256 = 3072 >= 2916)

// ---------------------------------------------------------------------------
// Kernel A: depthwise 3x3 conv + bias + BN + ReLU, per-(b,c) map max.
// Writes y map to workspace only if max >= DW_THRESH; writes flag always.
// ---------------------------------------------------------------------------
__global__ __launch_bounds__(256) void dw_kernel(
    const float* __restrict__ x,
    const float* __restrict__ dw_w, const float* __restrict__ dw_b,
    const float* __restrict__ dw_g, const float* __restrict__ dw_be,
    const float* __restrict__ dw_mean, const float* __restrict__ dw_var,
    float* __restrict__ y, int* __restrict__ flags)
{
    const int c = blockIdx.x;
    const int b = blockIdx.y;
    const int tid = threadIdx.x;

    __shared__ float sx[XPIX];     // 12.25 KB
    __shared__ float sred[256];

    const float* xp = x + (size_t)(b * CIN + c) * XPIX;
    for (int i = tid; i < XPIX; i += 256) sx[i] = xp[i];

    float w[9];
#pragma unroll
    for (int k = 0; k < 9; ++k) w[k] = dw_w[c * 9 + k];
    const float scale = dw_g[c] * rsqrtf(dw_var[c] + EPS_BN);
    const float shift = dw_be[c] - dw_mean[c] * scale + dw_b[c] * scale;

    __syncthreads();

    float r[PPT];
    float mx = 0.f;
#pragma unroll
    for (int j = 0; j < PPT; ++j) {
        const int idx = tid + j * 256;
        float v = 0.f;
        if (idx < NPIX) {
            const int oh = idx / WOUT;
            const int ow = idx - oh * WOUT;
            const float* p = &sx[oh * WIN + ow];
            float acc = 0.f;
#pragma unroll
            for (int kh = 0; kh < 3; ++kh)
#pragma unroll
                for (int kw = 0; kw < 3; ++kw)
                    acc = fmaf(p[kh * WIN + kw], w[kh * 3 + kw], acc);
            v = fmaf(acc, scale, shift);
            v = v > 0.f ? v : 0.f;   // relu; values now >= 0 so max == maxabs
        }
        r[j] = v;
        mx = fmaxf(mx, v);
    }

    // block max reduction
    sred[tid] = mx;
    __syncthreads();
#pragma unroll
    for (int s = 128; s > 0; s >>= 1) {
        if (tid < s) sred[tid] = fmaxf(sred[tid], sred[tid + s]);
        __syncthreads();
    }
    const float bm = sred[0];

    const int fidx = b * CIN + c;
    if (bm >= DW_THRESH) {
        float* yp = y + (size_t)fidx * NPIX;
#pragma unroll
        for (int j = 0; j < PPT; ++j) {
            const int idx = tid + j * 256;
            if (idx < NPIX) yp[idx] = r[j];
        }
        if (tid == 0) flags[fidx] = 1;
    } else {
        if (tid == 0) flags[fidx] = 0;
    }
}

// ---------------------------------------------------------------------------
// Kernel B: pointwise 1x1 conv over flagged channels + bias + BN + ReLU,
// per-(b,o) map max, cut at PW_THRESH. Always writes all NPIX outputs.
// ---------------------------------------------------------------------------
__global__ __launch_bounds__(256) void pw_kernel(
    const float* __restrict__ y, const int* __restrict__ flags,
    const float* __restrict__ pw_w, const float* __restrict__ pw_b,
    const float* __restrict__ pw_g, const float* __restrict__ pw_be,
    const float* __restrict__ pw_mean, const float* __restrict__ pw_var,
    float* __restrict__ out)
{
    const int o = blockIdx.x;
    const int b = blockIdx.y;
    const int tid = threadIdx.x;

    __shared__ int   sflag[CIN];
    __shared__ float sred[256];

    sflag[tid] = flags[b * CIN + tid];   // CIN == 256 == blockDim
    __syncthreads();

    float acc[PPT];
#pragma unroll
    for (int j = 0; j < PPT; ++j) acc[j] = 0.f;

    const float* wrow = pw_w + (size_t)o * CIN;
    for (int c = 0; c < CIN; ++c) {
        if (sflag[c]) {                          // block-uniform branch
            const float wv = wrow[c];
            const float* yp = y + (size_t)(b * CIN + c) * NPIX;
#pragma unroll
            for (int j = 0; j < PPT; ++j) {
                const int idx = tid + j * 256;
                if (idx < NPIX) acc[j] = fmaf(yp[idx], wv, acc[j]);
            }
        }
    }

    const float scale = pw_g[o] * rsqrtf(pw_var[o] + EPS_BN);
    const float shift = pw_be[o] - pw_mean[o] * scale + pw_b[o] * scale;

    float r[PPT];
    float mx = 0.f;
#pragma unroll
    for (int j = 0; j < PPT; ++j) {
        float v = fmaf(acc[j], scale, shift);
        v = v > 0.f ? v : 0.f;
        r[j] = v;
        mx = fmaxf(mx, v);
    }

    sred[tid] = mx;
    __syncthreads();
#pragma unroll
    for (int s = 128; s > 0; s >>= 1) {
        if (tid < s) sred[tid] = fmaxf(sred[tid], sred[tid + s]);
        __syncthreads();
    }
    const float bm = sred[0];
    const bool keep = (bm >= PW_THRESH);

    float* op = out + (size_t)(b * COUT + o) * NPIX;
#pragma unroll
    for (int j = 0; j < PPT; ++j) {
        const int idx = tid + j * 256;
        if (idx < NPIX) op[idx] = keep ? r[j] : 0.f;
    }
}

// ---------------------------------------------------------------------------
extern "C" void kernel_launch(void* const* d_in, const int* in_sizes, int n_in,
                              void* d_out, int out_size, void* d_ws, size_t ws_size,
                              hipStream_t stream) {
    const float* x       = (const float*)d_in[0];
    const float* dw_w    = (const float*)d_in[1];
    const float* dw_b    = (const float*)d_in[2];
    const float* dw_g    = (const float*)d_in[3];
    const float* dw_be   = (const float*)d_in[4];
    const float* dw_mean = (const float*)d_in[5];
    const float* dw_var  = (const float*)d_in[6];
    const float* pw_w    = (const float*)d_in[7];
    const float* pw_b    = (const float*)d_in[8];
    const float* pw_g    = (const float*)d_in[9];
    const float* pw_be   = (const float*)d_in[10];
    const float* pw_mean = (const float*)d_in[11];
    const float* pw_var  = (const float*)d_in[12];

    float* out = (float*)d_out;

    // workspace layout: y (B*CIN*NPIX floats) then flags (B*CIN ints)
    float* y = (float*)d_ws;
    int* flags = (int*)((char*)d_ws + (size_t)BATCH * CIN * NPIX * sizeof(float));

    dim3 gridA(CIN, BATCH);
    hipLaunchKernelGGL(dw_kernel, gridA, dim3(256), 0, stream,
                       x, dw_w, dw_b, dw_g, dw_be, dw_mean, dw_var, y, flags);

    dim3 gridB(COUT, BATCH);
    hipLaunchKernelGGL(pw_kernel, gridB, dim3(256), 0, stream,
                       y, flags, pw_w, pw_b, pw_g, pw_be, pw_mean, pw_var, out);
}

// Round 2
// 72.303 us; speedup vs baseline: 3.5272x; 3.5272x over previous
//
#include <hip/hip_runtime.h>
#include <hip/hip_bf16.h>

#define EPS_BN 1e-5f
#define DW_THRESH 4.0f
#define PW_THRESH 0.001f

// Problem dims (fixed by the reference)
#define BATCH 32
#define CIN   256
#define COUT  512
#define HIN   56
#define WIN   56
#define HOUT  54
#define WOUT  54
#define NPIX  (HOUT*WOUT)     // 2916
#define XPIX  (HIN*WIN)       // 3136
#define NG    (HOUT*14)       // 756 groups of 4 output pixels (14 groups/row)
#define PPT   12              // pixels per thread in slow pw path

// ---------------------------------------------------------------------------
// Kernel 0: zero the per-batch survivor counters.
// ---------------------------------------------------------------------------
__global__ void init_kernel(int* __restrict__ bcount) {
    if (threadIdx.x < BATCH) bcount[threadIdx.x] = 0;
}

// ---------------------------------------------------------------------------
// Kernel A: depthwise 3x3 conv + bias + BN + ReLU, per-(b,c) map max.
// Writes y map to workspace only if max >= DW_THRESH; writes flag always;
// bumps per-batch survivor count.
// ---------------------------------------------------------------------------
__global__ __launch_bounds__(256) void dw_kernel(
    const float* __restrict__ x,
    const float* __restrict__ dw_w, const float* __restrict__ dw_b,
    const float* __restrict__ dw_g, const float* __restrict__ dw_be,
    const float* __restrict__ dw_mean, const float* __restrict__ dw_var,
    float* __restrict__ y, int* __restrict__ flags, int* __restrict__ bcount)
{
    const int c = blockIdx.x;
    const int b = blockIdx.y;
    const int tid = threadIdx.x;

    __shared__ float sx[XPIX + 8];   // +8 pad: float4 overread at row 55, gcol 52
    __shared__ float sred[256];

    const float* xp = x + (size_t)(b * CIN + c) * XPIX;
    const float4* xp4 = (const float4*)xp;
    float4* sx4 = (float4*)sx;
#pragma unroll
    for (int i = 0; i < 4; ++i) {
        const int idx = tid + i * 256;
        if (idx < XPIX / 4) sx4[idx] = xp4[idx];   // 784 float4
    }

    float w[9];
#pragma unroll
    for (int k = 0; k < 9; ++k) w[k] = dw_w[c * 9 + k];
    const float scale = dw_g[c] * rsqrtf(dw_var[c] + EPS_BN);
    const float shift = dw_be[c] - dw_mean[c] * scale + dw_b[c] * scale;

    __syncthreads();

    float r[3][4];
    float mx = 0.f;
#pragma unroll
    for (int jg = 0; jg < 3; ++jg) {
        const int G = tid + jg * 256;
        r[jg][0] = r[jg][1] = r[jg][2] = r[jg][3] = 0.f;
        if (G < NG) {
            const int row  = G / 14;
            const int gcol = (G - row * 14) * 4;
            const float* p0 = &sx[row * WIN + gcol];
            const float4 x00 = *(const float4*)(p0);
            const float4 x01 = *(const float4*)(p0 + 4);
            const float4 x10 = *(const float4*)(p0 + WIN);
            const float4 x11 = *(const float4*)(p0 + WIN + 4);
            const float4 x20 = *(const float4*)(p0 + 2 * WIN);
            const float4 x21 = *(const float4*)(p0 + 2 * WIN + 4);
            const float a0[8] = {x00.x, x00.y, x00.z, x00.w, x01.x, x01.y, x01.z, x01.w};
            const float a1[8] = {x10.x, x10.y, x10.z, x10.w, x11.x, x11.y, x11.z, x11.w};
            const float a2[8] = {x20.x, x20.y, x20.z, x20.w, x21.x, x21.y, x21.z, x21.w};
#pragma unroll
            for (int p = 0; p < 4; ++p) {
                float acc;
                acc = a0[p] * w[0];
                acc = fmaf(a0[p + 1], w[1], acc);
                acc = fmaf(a0[p + 2], w[2], acc);
                acc = fmaf(a1[p],     w[3], acc);
                acc = fmaf(a1[p + 1], w[4], acc);
                acc = fmaf(a1[p + 2], w[5], acc);
                acc = fmaf(a2[p],     w[6], acc);
                acc = fmaf(a2[p + 1], w[7], acc);
                acc = fmaf(a2[p + 2], w[8], acc);
                float v = fmaf(acc, scale, shift);
                v = v > 0.f ? v : 0.f;   // relu -> values >= 0, max == maxabs
                if (gcol + p < WOUT) {
                    r[jg][p] = v;
                    mx = fmaxf(mx, v);
                }
            }
        }
    }

    // block max reduction
    sred[tid] = mx;
    __syncthreads();
#pragma unroll
    for (int s = 128; s > 0; s >>= 1) {
        if (tid < s) sred[tid] = fmaxf(sred[tid], sred[tid + s]);
        __syncthreads();
    }
    const float bm = sred[0];

    const int fidx = b * CIN + c;
    if (bm >= DW_THRESH) {
        float* yp = y + (size_t)fidx * NPIX;
#pragma unroll
        for (int jg = 0; jg < 3; ++jg) {
            const int G = tid + jg * 256;
            if (G < NG) {
                const int row  = G / 14;
                const int gcol = (G - row * 14) * 4;
#pragma unroll
                for (int p = 0; p < 4; ++p) {
                    const int col = gcol + p;
                    if (col < WOUT) yp[row * WOUT + col] = r[jg][p];
                }
            }
        }
        if (tid == 0) { flags[fidx] = 1; atomicAdd(&bcount[b], 1); }
    } else {
        if (tid == 0) flags[fidx] = 0;
    }
}

// ---------------------------------------------------------------------------
// Kernel B: pointwise 1x1 conv over flagged channels + bias + BN + ReLU,
// per-(b,o) map max, cut at PW_THRESH. Always writes all NPIX outputs.
// Fast path when the batch has zero surviving channels: block-uniform value.
// ---------------------------------------------------------------------------
__global__ __launch_bounds__(256) void pw_kernel(
    const float* __restrict__ y, const int* __restrict__ flags,
    const int* __restrict__ bcount,
    const float* __restrict__ pw_w, const float* __restrict__ pw_b,
    const float* __restrict__ pw_g, const float* __restrict__ pw_be,
    const float* __restrict__ pw_mean, const float* __restrict__ pw_var,
    float* __restrict__ out)
{
    const int o = blockIdx.x;
    const int b = blockIdx.y;
    const int tid = threadIdx.x;

    const float scale = pw_g[o] * rsqrtf(pw_var[o] + EPS_BN);
    const float shift = pw_be[o] - pw_mean[o] * scale + pw_b[o] * scale;

    if (bcount[b] == 0) {
        // acc == 0 for every pixel: v = relu(shift), uniform over the map.
        float v = shift > 0.f ? shift : 0.f;
        const float val = (v >= PW_THRESH) ? v : 0.f;
        float4* op = (float4*)(out + (size_t)(b * COUT + o) * NPIX);  // 729 float4
        const float4 f = make_float4(val, val, val, val);
#pragma unroll
        for (int j = 0; j < 3; ++j) {
            const int idx = tid + j * 256;
            if (idx < NPIX / 4) op[idx] = f;
        }
        return;
    }

    // ---- generic path (some channels survived) ----
    __shared__ int   sflag[CIN];
    __shared__ float sred[256];

    sflag[tid] = flags[b * CIN + tid];   // CIN == 256 == blockDim
    __syncthreads();

    float acc[PPT];
#pragma unroll
    for (int j = 0; j < PPT; ++j) acc[j] = 0.f;

    const float* wrow = pw_w + (size_t)o * CIN;
    for (int c = 0; c < CIN; ++c) {
        if (sflag[c]) {                          // block-uniform branch
            const float wv = wrow[c];
            const float* yp = y + (size_t)(b * CIN + c) * NPIX;
#pragma unroll
            for (int j = 0; j < PPT; ++j) {
                const int idx = tid + j * 256;
                if (idx < NPIX) acc[j] = fmaf(yp[idx], wv, acc[j]);
            }
        }
    }

    float r[PPT];
    float mx = 0.f;
#pragma unroll
    for (int j = 0; j < PPT; ++j) {
        float v = fmaf(acc[j], scale, shift);
        v = v > 0.f ? v : 0.f;
        r[j] = v;
        mx = fmaxf(mx, v);
    }

    sred[tid] = mx;
    __syncthreads();
#pragma unroll
    for (int s = 128; s > 0; s >>= 1) {
        if (tid < s) sred[tid] = fmaxf(sred[tid], sred[tid + s]);
        __syncthreads();
    }
    const float bm = sred[0];
    const bool keep = (bm >= PW_THRESH);

    float* op = out + (size_t)(b * COUT + o) * NPIX;
#pragma unroll
    for (int j = 0; j < PPT; ++j) {
        const int idx = tid + j * 256;
        if (idx < NPIX) op[idx] = keep ? r[j] : 0.f;
    }
}

// ---------------------------------------------------------------------------
extern "C" void kernel_launch(void* const* d_in, const int* in_sizes, int n_in,
                              void* d_out, int out_size, void* d_ws, size_t ws_size,
                              hipStream_t stream) {
    const float* x       = (const float*)d_in[0];
    const float* dw_w    = (const float*)d_in[1];
    const float* dw_b    = (const float*)d_in[2];
    const float* dw_g    = (const float*)d_in[3];
    const float* dw_be   = (const float*)d_in[4];
    const float* dw_mean = (const float*)d_in[5];
    const float* dw_var  = (const float*)d_in[6];
    const float* pw_w    = (const float*)d_in[7];
    const float* pw_b    = (const float*)d_in[8];
    const float* pw_g    = (const float*)d_in[9];
    const float* pw_be   = (const float*)d_in[10];
    const float* pw_mean = (const float*)d_in[11];
    const float* pw_var  = (const float*)d_in[12];

    float* out = (float*)d_out;

    // workspace layout: y (B*CIN*NPIX floats), flags (B*CIN ints), bcount (B ints)
    float* y = (float*)d_ws;
    int* flags  = (int*)((char*)d_ws + (size_t)BATCH * CIN * NPIX * sizeof(float));
    int* bcount = flags + (size_t)BATCH * CIN;

    hipLaunchKernelGGL(init_kernel, dim3(1), dim3(64), 0, stream, bcount);

    dim3 gridA(CIN, BATCH);
    hipLaunchKernelGGL(dw_kernel, gridA, dim3(256), 0, stream,
                       x, dw_w, dw_b, dw_g, dw_be, dw_mean, dw_var, y, flags, bcount);

    dim3 gridB(COUT, BATCH);
    hipLaunchKernelGGL(pw_kernel, gridB, dim3(256), 0, stream,
                       y, flags, bcount, pw_w, pw_b, pw_g, pw_be, pw_mean, pw_var, out);
}

// Round 4
// 65.752 us; speedup vs baseline: 3.8786x; 1.0996x over previous
//
#include <hip/hip_runtime.h>
#include <hip/hip_bf16.h>

#define EPS_BN 1e-5f
#define DW_THRESH 4.0f
#define PW_THRESH 0.001f

// Problem dims (fixed by the reference)
#define BATCH 32
#define CIN   256
#define COUT  512
#define HIN   56
#define WIN   56
#define HOUT  54
#define WOUT  54
#define NPIX  (HOUT*WOUT)     // 2916
#define XPIX  (HIN*WIN)       // 3136
#define NG    (HOUT*14)       // 756 groups of 4 output pixels (14 groups/row)
#define PPT   12              // pixels per thread in slow pw path

// native clang vector type — accepted by __builtin_nontemporal_{load,store}
typedef float floatx4 __attribute__((ext_vector_type(4)));

// ---------------------------------------------------------------------------
// Kernel A: depthwise 3x3 conv + bias + BN + ReLU, per-(b,c) map max.
// Writes y map to workspace only if max >= DW_THRESH; always writes the
// per-map max to maxv[b*CIN+c].
// ---------------------------------------------------------------------------
__global__ __launch_bounds__(256) void dw_kernel(
    const float* __restrict__ x,
    const float* __restrict__ dw_w, const float* __restrict__ dw_b,
    const float* __restrict__ dw_g, const float* __restrict__ dw_be,
    const float* __restrict__ dw_mean, const float* __restrict__ dw_var,
    float* __restrict__ y, float* __restrict__ maxv)
{
    const int c = blockIdx.x;
    const int b = blockIdx.y;
    const int tid = threadIdx.x;

    __shared__ float sx[XPIX + 8];   // +8 pad: float4 overread at row 55, gcol 52
    __shared__ float swave[4];

    const float* xp = x + (size_t)(b * CIN + c) * XPIX;
    const floatx4* xp4 = (const floatx4*)xp;
    floatx4* sx4 = (floatx4*)sx;
#pragma unroll
    for (int i = 0; i < 4; ++i) {
        const int idx = tid + i * 256;
        if (idx < XPIX / 4) sx4[idx] = __builtin_nontemporal_load(&xp4[idx]);
    }

    float w[9];
#pragma unroll
    for (int k = 0; k < 9; ++k) w[k] = dw_w[c * 9 + k];
    const float scale = dw_g[c] * rsqrtf(dw_var[c] + EPS_BN);
    const float shift = dw_be[c] - dw_mean[c] * scale + dw_b[c] * scale;

    __syncthreads();

    float r[3][4];
    float mx = 0.f;
#pragma unroll
    for (int jg = 0; jg < 3; ++jg) {
        const int G = tid + jg * 256;
        r[jg][0] = r[jg][1] = r[jg][2] = r[jg][3] = 0.f;
        if (G < NG) {
            const int row  = G / 14;
            const int gcol = (G - row * 14) * 4;
            const float* p0 = &sx[row * WIN + gcol];
            const floatx4 x00 = *(const floatx4*)(p0);
            const floatx4 x01 = *(const floatx4*)(p0 + 4);
            const floatx4 x10 = *(const floatx4*)(p0 + WIN);
            const floatx4 x11 = *(const floatx4*)(p0 + WIN + 4);
            const floatx4 x20 = *(const floatx4*)(p0 + 2 * WIN);
            const floatx4 x21 = *(const floatx4*)(p0 + 2 * WIN + 4);
            const float a0[8] = {x00.x, x00.y, x00.z, x00.w, x01.x, x01.y, x01.z, x01.w};
            const float a1[8] = {x10.x, x10.y, x10.z, x10.w, x11.x, x11.y, x11.z, x11.w};
            const float a2[8] = {x20.x, x20.y, x20.z, x20.w, x21.x, x21.y, x21.z, x21.w};
#pragma unroll
            for (int p = 0; p < 4; ++p) {
                float acc;
                acc = a0[p] * w[0];
                acc = fmaf(a0[p + 1], w[1], acc);
                acc = fmaf(a0[p + 2], w[2], acc);
                acc = fmaf(a1[p],     w[3], acc);
                acc = fmaf(a1[p + 1], w[4], acc);
                acc = fmaf(a1[p + 2], w[5], acc);
                acc = fmaf(a2[p],     w[6], acc);
                acc = fmaf(a2[p + 1], w[7], acc);
                acc = fmaf(a2[p + 2], w[8], acc);
                float v = fmaf(acc, scale, shift);
                v = v > 0.f ? v : 0.f;   // relu -> values >= 0, max == maxabs
                if (gcol + p < WOUT) {
                    r[jg][p] = v;
                    mx = fmaxf(mx, v);
                }
            }
        }
    }

    // wave-level max reduction (64 lanes), then 4-wave exchange via LDS
#pragma unroll
    for (int off = 32; off > 0; off >>= 1)
        mx = fmaxf(mx, __shfl_xor(mx, off));
    if ((tid & 63) == 0) swave[tid >> 6] = mx;
    __syncthreads();
    const float bm = fmaxf(fmaxf(swave[0], swave[1]), fmaxf(swave[2], swave[3]));

    const int fidx = b * CIN + c;
    if (tid == 0) maxv[fidx] = bm;

    if (bm >= DW_THRESH) {
        float* yp = y + (size_t)fidx * NPIX;
#pragma unroll
        for (int jg = 0; jg < 3; ++jg) {
            const int G = tid + jg * 256;
            if (G < NG) {
                const int row  = G / 14;
                const int gcol = (G - row * 14) * 4;
#pragma unroll
                for (int p = 0; p < 4; ++p) {
                    const int col = gcol + p;
                    if (col < WOUT) yp[row * WOUT + col] = r[jg][p];
                }
            }
        }
    }
}

// ---------------------------------------------------------------------------
// Kernel B: pointwise 1x1 conv over surviving channels + bias + BN + ReLU,
// per-(b,o) map max, cut at PW_THRESH. Always writes all NPIX outputs.
// Fast path when the batch has zero surviving channels: block-uniform value.
// ---------------------------------------------------------------------------
__global__ __launch_bounds__(256) void pw_kernel(
    const float* __restrict__ y, const float* __restrict__ maxv,
    const float* __restrict__ pw_w, const float* __restrict__ pw_b,
    const float* __restrict__ pw_g, const float* __restrict__ pw_be,
    const float* __restrict__ pw_mean, const float* __restrict__ pw_var,
    float* __restrict__ out)
{
    const int o = blockIdx.x;
    const int b = blockIdx.y;
    const int tid = threadIdx.x;

    __shared__ int   sflag[CIN];
    __shared__ float sred[256];

    const int flag = (maxv[b * CIN + tid] >= DW_THRESH) ? 1 : 0;  // CIN==blockDim
    sflag[tid] = flag;
    const int nsurv = __syncthreads_count(flag);

    const float scale = pw_g[o] * rsqrtf(pw_var[o] + EPS_BN);
    const float shift = pw_be[o] - pw_mean[o] * scale + pw_b[o] * scale;

    if (nsurv == 0) {
        // acc == 0 for every pixel: v = relu(shift), uniform over the map.
        float v = shift > 0.f ? shift : 0.f;
        const float val = (v >= PW_THRESH) ? v : 0.f;
        floatx4* op = (floatx4*)(out + (size_t)(b * COUT + o) * NPIX);  // 729 float4
        floatx4 f;
        f.x = val; f.y = val; f.z = val; f.w = val;
#pragma unroll
        for (int j = 0; j < 3; ++j) {
            const int idx = tid + j * 256;
            if (idx < NPIX / 4) __builtin_nontemporal_store(f, &op[idx]);
        }
        return;
    }

    // ---- generic path (some channels survived) ----
    float acc[PPT];
#pragma unroll
    for (int j = 0; j < PPT; ++j) acc[j] = 0.f;

    const float* wrow = pw_w + (size_t)o * CIN;
    for (int c = 0; c < CIN; ++c) {
        if (sflag[c]) {                          // block-uniform branch
            const float wv = wrow[c];
            const float* yp = y + (size_t)(b * CIN + c) * NPIX;
#pragma unroll
            for (int j = 0; j < PPT; ++j) {
                const int idx = tid + j * 256;
                if (idx < NPIX) acc[j] = fmaf(yp[idx], wv, acc[j]);
            }
        }
    }

    float r[PPT];
    float mx = 0.f;
#pragma unroll
    for (int j = 0; j < PPT; ++j) {
        float v = fmaf(acc[j], scale, shift);
        v = v > 0.f ? v : 0.f;
        r[j] = v;
        mx = fmaxf(mx, v);
    }

    sred[tid] = mx;
    __syncthreads();
#pragma unroll
    for (int s = 128; s > 0; s >>= 1) {
        if (tid < s) sred[tid] = fmaxf(sred[tid], sred[tid + s]);
        __syncthreads();
    }
    const float bm = sred[0];
    const bool keep = (bm >= PW_THRESH);

    float* op = out + (size_t)(b * COUT + o) * NPIX;
#pragma unroll
    for (int j = 0; j < PPT; ++j) {
        const int idx = tid + j * 256;
        if (idx < NPIX) op[idx] = keep ? r[j] : 0.f;
    }
}

// ---------------------------------------------------------------------------
extern "C" void kernel_launch(void* const* d_in, const int* in_sizes, int n_in,
                              void* d_out, int out_size, void* d_ws, size_t ws_size,
                              hipStream_t stream) {
    const float* x       = (const float*)d_in[0];
    const float* dw_w    = (const float*)d_in[1];
    const float* dw_b    = (const float*)d_in[2];
    const float* dw_g    = (const float*)d_in[3];
    const float* dw_be   = (const float*)d_in[4];
    const float* dw_mean = (const float*)d_in[5];
    const float* dw_var  = (const float*)d_in[6];
    const float* pw_w    = (const float*)d_in[7];
    const float* pw_b    = (const float*)d_in[8];
    const float* pw_g    = (const float*)d_in[9];
    const float* pw_be   = (const float*)d_in[10];
    const float* pw_mean = (const float*)d_in[11];
    const float* pw_var  = (const float*)d_in[12];

    float* out = (float*)d_out;

    // workspace layout: y (B*CIN*NPIX floats), maxv (B*CIN floats)
    float* y = (float*)d_ws;
    float* maxv = (float*)((char*)d_ws + (size_t)BATCH * CIN * NPIX * sizeof(float));

    dim3 gridA(CIN, BATCH);
    hipLaunchKernelGGL(dw_kernel, gridA, dim3(256), 0, stream,
                       x, dw_w, dw_b, dw_g, dw_be, dw_mean, dw_var, y, maxv);

    dim3 gridB(COUT, BATCH);
    hipLaunchKernelGGL(pw_kernel, gridB, dim3(256), 0, stream,
                       y, maxv, pw_w, pw_b, pw_g, pw_be, pw_mean, pw_var, out);
}